// Round 7
// baseline (306.567 us; speedup 1.0000x reference)
//
#include <hip/hip_runtime.h>

#define B_ 2
#define T_ 4096
#define D_ 256
#define H_ 8
#define DK_ 32
#define EPS_ 1e-5f

typedef __attribute__((ext_vector_type(8))) __bf16 bf16x8;
typedef __attribute__((ext_vector_type(4))) float f32x4;

// 1/sqrt(32) * log2(e): folded into Q so softmax uses raw v_exp_f32 (2^x)
#define QSCALE 0.25503497f

__device__ inline unsigned short f2bf(float f) {
  unsigned int u = __float_as_uint(f);
  unsigned int r = (u + 0x7fffu + ((u >> 16) & 1u)) >> 16;  // RNE
  return (unsigned short)r;
}

__device__ inline f32x4 mfma16(bf16x8 a, bf16x8 b, f32x4 c) {
  return __builtin_amdgcn_mfma_f32_16x16x32_bf16(a, b, c, 0, 0, 0);
}

// ---- prep: fold BN into depthwise conv weights/bias ----
__global__ void prep_bn(const float* __restrict__ dw_w, const float* __restrict__ dw_b,
                        const float* __restrict__ gma, const float* __restrict__ bta,
                        const float* __restrict__ mu, const float* __restrict__ var,
                        float* __restrict__ wf, float* __restrict__ yb) {
  int i = blockIdx.x * blockDim.x + threadIdx.x;  // p*D + c, 768 total
  if (i >= 3 * D_) return;
  float s = gma[i] * rsqrtf(var[i] + EPS_);
  wf[i * 3 + 0] = dw_w[i * 3 + 0] * s;
  wf[i * 3 + 1] = dw_w[i * 3 + 1] * s;
  wf[i * 3 + 2] = dw_w[i * 3 + 2] * s;
  yb[i] = (dw_b[i] - mu[i]) * s + bta[i];
}

// ---- convert pointwise / output weights to bf16 ----
__global__ void cvt_w(const float* __restrict__ pw_w, const float* __restrict__ out_w,
                      unsigned short* __restrict__ Wb, unsigned short* __restrict__ Ob) {
  int i = blockIdx.x * blockDim.x + threadIdx.x;
  if (i < 3 * D_ * D_) Wb[i] = f2bf(pw_w[i]);
  if (i < D_ * D_) Ob[i] = f2bf(out_w[i]);
}

// ---- depthwise conv (K=3, pad same) + BN -> Y bf16 [3][B*T][D] ----
__global__ __launch_bounds__(256) void conv_bn(const float* __restrict__ x,
                                               const float* __restrict__ wf,
                                               const float* __restrict__ yb,
                                               unsigned short* __restrict__ Y) {
  int bt = blockIdx.x;        // b*T + t
  int c = threadIdx.x;        // 0..255
  int t = bt & (T_ - 1);
  const float* xp = x + (size_t)bt * D_ + c;
  float x0 = xp[0];
  float xm = (t > 0) ? xp[-D_] : 0.f;
  float xq = (t < T_ - 1) ? xp[D_] : 0.f;
#pragma unroll
  for (int p = 0; p < 3; ++p) {
    int pc = p * D_ + c;
    float y = fmaf(xm, wf[pc * 3 + 0],
              fmaf(x0, wf[pc * 3 + 1],
              fmaf(xq, wf[pc * 3 + 2], yb[pc])));
    Y[(size_t)p * (B_ * T_ * D_) + (size_t)bt * D_ + c] = f2bf(y);
  }
}

// ---- QKV pointwise GEMM: Z[p] = Y[p] (8192x256) * Wb[p]^T (256x256) + pw_b ----
// Q (pre-scaled) and K as [b][h][t][dk].
// V (p==2): swapped operands mfma(A=W, B=Y) -> C[o][t], so Vt[b][h][dk][t]
// stores are 32B-contiguous per 16-lane group (was 2-byte stride-8KB scatter).
__global__ __launch_bounds__(256) void qkv_gemm(const unsigned short* __restrict__ Y,
                                                const unsigned short* __restrict__ Wb,
                                                const float* __restrict__ pw_b,
                                                unsigned short* __restrict__ Q,
                                                unsigned short* __restrict__ Kk,
                                                unsigned short* __restrict__ Vt) {
  int p = blockIdx.y;
  int m0 = blockIdx.x * 16;
  int wv = threadIdx.x >> 6;
  int lane = threadIdx.x & 63;
  int lm = lane & 15, g = lane >> 4;
  int n0 = wv * 64;
  const unsigned short* Yp = Y + (size_t)p * (B_ * T_ * D_);
  const unsigned short* Wp = Wb + (size_t)p * (D_ * D_);
  f32x4 acc[4] = {};

  if (p < 2) {
    for (int k0 = 0; k0 < D_; k0 += 32) {
      bf16x8 a = *reinterpret_cast<const bf16x8*>(Yp + (size_t)(m0 + lm) * D_ + k0 + 8 * g);
#pragma unroll
      for (int j = 0; j < 4; ++j) {
        bf16x8 b = *reinterpret_cast<const bf16x8*>(Wp + (size_t)(n0 + j * 16 + lm) * D_ + k0 + 8 * g);
        acc[j] = mfma16(a, b, acc[j]);
      }
    }
    float scl = (p == 0) ? QSCALE : 1.0f;
#pragma unroll
    for (int j = 0; j < 4; ++j) {
      int o = n0 + j * 16 + lm;
      float bias = pw_b[p * D_ + o];
      int h = o >> 5, dk = o & 31;
#pragma unroll
      for (int r = 0; r < 4; ++r) {
        int row = m0 + g * 4 + r;  // b*T + t
        int b = row >> 12, t = row & (T_ - 1);
        unsigned short bv = f2bf((acc[j][r] + bias) * scl);
        size_t bh = (size_t)(b * H_ + h);
        if (p == 0)
          Q[(bh * T_ + t) * DK_ + dk] = bv;
        else
          Kk[(bh * T_ + t) * DK_ + dk] = bv;
      }
    }
  } else {
    // V path: A=W rows (o), B=Y rows (t) -> C[row=o local 4g+r][col=t lm]
    for (int k0 = 0; k0 < D_; k0 += 32) {
      bf16x8 by = *reinterpret_cast<const bf16x8*>(Yp + (size_t)(m0 + lm) * D_ + k0 + 8 * g);
#pragma unroll
      for (int j = 0; j < 4; ++j) {
        bf16x8 aw = *reinterpret_cast<const bf16x8*>(Wp + (size_t)(n0 + j * 16 + lm) * D_ + k0 + 8 * g);
        acc[j] = mfma16(aw, by, acc[j]);
      }
    }
    int row = m0 + lm;  // b*T + t
    int b = row >> 12, t = row & (T_ - 1);
#pragma unroll
    for (int j = 0; j < 4; ++j) {
#pragma unroll
      for (int r = 0; r < 4; ++r) {
        int o = n0 + j * 16 + 4 * g + r;
        int h = o >> 5, dk = o & 31;
        unsigned short bv = f2bf(acc[j][r] + pw_b[2 * D_ + o]);
        Vt[((size_t)(b * H_ + h) * DK_ + dk) * T_ + t] = bv;
      }
    }
  }
}

// ---- flash attention: swapped QK^T, in-register softmax, register prefetch ----
// One wave per 16 q-rows. Scores via mfma(K,Q): lane(lm,g) holds q-row lm.
// K rows loaded permuted (ra, ra+4) so each lane's P lands directly in
// PV A-fragment layout (keys 8g..8g+7). K/V for iter k+1 prefetched into
// registers while computing iter k (counted-vmcnt overlap). Row-sum l is
// computed by MFMA against a ones vector -> lacc in acc layout (q=4g+r).
__global__ __launch_bounds__(256) void attn(const unsigned short* __restrict__ Q,
                                            const unsigned short* __restrict__ Kk,
                                            const unsigned short* __restrict__ Vt,
                                            unsigned short* __restrict__ ctx) {
  int wv = threadIdx.x >> 6, lane = threadIdx.x & 63;
  int lm = lane & 15, g = lane >> 4;
  int wid = blockIdx.x * 4 + wv;  // 0..4095
  int bh = wid >> 8;              // b*H + h
  int qt = wid & 255;
  int q0 = qt * 16;
  const unsigned short* Qh = Q + (size_t)bh * (T_ * DK_);
  const unsigned short* Kh = Kk + (size_t)bh * (T_ * DK_);
  const unsigned short* Vh = Vt + (size_t)bh * (DK_ * T_);

  // Q fragment (B operand): lane holds Q[q0+lm][8g..8g+7]
  bf16x8 qf = *reinterpret_cast<const bf16x8*>(Qh + (size_t)(q0 + lm) * DK_ + 8 * g);

  const int ra = 8 * (lm >> 2) + (lm & 3);  // permuted K row for score A-frag
  const unsigned short* Kp = Kh + (size_t)ra * DK_ + 8 * g;
  const unsigned short* Vp = Vh + (size_t)lm * T_ + 8 * g;

  bf16x8 one8;
#pragma unroll
  for (int i = 0; i < 8; ++i) one8[i] = (__bf16)1.0f;

  float mrow = -1e30f;
  f32x4 lacc = {};
  f32x4 acc_lo = {}, acc_hi = {};

  // preload iteration 0
  bf16x8 kA0 = *reinterpret_cast<const bf16x8*>(Kp);
  bf16x8 kA1 = *reinterpret_cast<const bf16x8*>(Kp + (size_t)4 * DK_);
  bf16x8 kB0 = *reinterpret_cast<const bf16x8*>(Kp + (size_t)32 * DK_);
  bf16x8 kB1 = *reinterpret_cast<const bf16x8*>(Kp + (size_t)36 * DK_);
  bf16x8 v00 = *reinterpret_cast<const bf16x8*>(Vp);
  bf16x8 v10 = *reinterpret_cast<const bf16x8*>(Vp + 32);
  bf16x8 v01 = *reinterpret_cast<const bf16x8*>(Vp + 16 * T_);
  bf16x8 v11 = *reinterpret_cast<const bf16x8*>(Vp + 16 * T_ + 32);

  for (int k0 = 0; k0 < T_; k0 += 64) {
    // prefetch next iteration's K/V (wraps to 0 on the last iter; harmless)
    int kn = (k0 + 64) & (T_ - 1);
    bf16x8 nA0 = *reinterpret_cast<const bf16x8*>(Kp + (size_t)kn * DK_);
    bf16x8 nA1 = *reinterpret_cast<const bf16x8*>(Kp + (size_t)(kn + 4) * DK_);
    bf16x8 nB0 = *reinterpret_cast<const bf16x8*>(Kp + (size_t)(kn + 32) * DK_);
    bf16x8 nB1 = *reinterpret_cast<const bf16x8*>(Kp + (size_t)(kn + 36) * DK_);
    bf16x8 w00 = *reinterpret_cast<const bf16x8*>(Vp + kn);
    bf16x8 w10 = *reinterpret_cast<const bf16x8*>(Vp + kn + 32);
    bf16x8 w01 = *reinterpret_cast<const bf16x8*>(Vp + 16 * T_ + kn);
    bf16x8 w11 = *reinterpret_cast<const bf16x8*>(Vp + 16 * T_ + kn + 32);

    f32x4 z = {};
    f32x4 sA0 = mfma16(kA0, qf, z);  // keys k0+8g+r
    f32x4 sA1 = mfma16(kA1, qf, z);  // keys k0+8g+4+r
    f32x4 sB0 = mfma16(kB0, qf, z);  // keys k0+32+8g+r
    f32x4 sB1 = mfma16(kB1, qf, z);  // keys k0+32+8g+4+r

    float mx = fmaxf(
        fmaxf(fmaxf(fmaxf(sA0[0], sA0[1]), fmaxf(sA0[2], sA0[3])),
              fmaxf(fmaxf(sA1[0], sA1[1]), fmaxf(sA1[2], sA1[3]))),
        fmaxf(fmaxf(fmaxf(sB0[0], sB0[1]), fmaxf(sB0[2], sB0[3])),
              fmaxf(fmaxf(sB1[0], sB1[1]), fmaxf(sB1[2], sB1[3]))));
    mx = fmaxf(mx, __shfl_xor(mx, 16));
    mx = fmaxf(mx, __shfl_xor(mx, 32));

    // defer-max (T13): only rescale when the row max grew by >8 (log2 units)
    if (!__all(mx <= mrow + 8.f)) {
      float mn = fmaxf(mrow, mx);
      float al = __builtin_amdgcn_exp2f(mrow - mn);
      mrow = mn;
      float al0 = __shfl(al, 4 * g + 0);
      float al1 = __shfl(al, 4 * g + 1);
      float al2 = __shfl(al, 4 * g + 2);
      float al3 = __shfl(al, 4 * g + 3);
      lacc[0] *= al0; acc_lo[0] *= al0; acc_hi[0] *= al0;
      lacc[1] *= al1; acc_lo[1] *= al1; acc_hi[1] *= al1;
      lacc[2] *= al2; acc_lo[2] *= al2; acc_hi[2] *= al2;
      lacc[3] *= al3; acc_lo[3] *= al3; acc_hi[3] *= al3;
    }

    bf16x8 pfA, pfB;
    pfA[0] = (__bf16)__builtin_amdgcn_exp2f(sA0[0] - mrow);
    pfA[1] = (__bf16)__builtin_amdgcn_exp2f(sA0[1] - mrow);
    pfA[2] = (__bf16)__builtin_amdgcn_exp2f(sA0[2] - mrow);
    pfA[3] = (__bf16)__builtin_amdgcn_exp2f(sA0[3] - mrow);
    pfA[4] = (__bf16)__builtin_amdgcn_exp2f(sA1[0] - mrow);
    pfA[5] = (__bf16)__builtin_amdgcn_exp2f(sA1[1] - mrow);
    pfA[6] = (__bf16)__builtin_amdgcn_exp2f(sA1[2] - mrow);
    pfA[7] = (__bf16)__builtin_amdgcn_exp2f(sA1[3] - mrow);
    pfB[0] = (__bf16)__builtin_amdgcn_exp2f(sB0[0] - mrow);
    pfB[1] = (__bf16)__builtin_amdgcn_exp2f(sB0[1] - mrow);
    pfB[2] = (__bf16)__builtin_amdgcn_exp2f(sB0[2] - mrow);
    pfB[3] = (__bf16)__builtin_amdgcn_exp2f(sB0[3] - mrow);
    pfB[4] = (__bf16)__builtin_amdgcn_exp2f(sB1[0] - mrow);
    pfB[5] = (__bf16)__builtin_amdgcn_exp2f(sB1[1] - mrow);
    pfB[6] = (__bf16)__builtin_amdgcn_exp2f(sB1[2] - mrow);
    pfB[7] = (__bf16)__builtin_amdgcn_exp2f(sB1[3] - mrow);

    // l via MFMA: lacc[r] += sum_k P[q=4g+r][k]  (replicated over lm)
    lacc = mfma16(pfA, one8, lacc);
    lacc = mfma16(pfB, one8, lacc);

    acc_lo = mfma16(pfA, v00, acc_lo);
    acc_lo = mfma16(pfB, v10, acc_lo);
    acc_hi = mfma16(pfA, v01, acc_hi);
    acc_hi = mfma16(pfB, v11, acc_hi);

    kA0 = nA0; kA1 = nA1; kB0 = nB0; kB1 = nB1;
    v00 = w00; v10 = w10; v01 = w01; v11 = w11;
  }

  int b = bh >> 3, h = bh & 7;
  // lacc[r] = l for q = q0+4g+r  — exactly the acc row layout, no shuffles
  f32x4 inv;
#pragma unroll
  for (int r = 0; r < 4; ++r) inv[r] = 1.f / lacc[r];
  {
    int t = q0 + 4 * g;
    size_t base = ((size_t)(b * T_ + t)) * D_ + h * DK_;
    ctx[base + lm] = f2bf(acc_lo[0] * inv[0]);
    ctx[base + 16 + lm] = f2bf(acc_hi[0] * inv[0]);
    base += D_;
    ctx[base + lm] = f2bf(acc_lo[1] * inv[1]);
    ctx[base + 16 + lm] = f2bf(acc_hi[1] * inv[1]);
    base += D_;
    ctx[base + lm] = f2bf(acc_lo[2] * inv[2]);
    ctx[base + 16 + lm] = f2bf(acc_hi[2] * inv[2]);
    base += D_;
    ctx[base + lm] = f2bf(acc_lo[3] * inv[3]);
    ctx[base + 16 + lm] = f2bf(acc_hi[3] * inv[3]);
  }
}

// ---- output projection: out = ctx (8192x256) * Ob^T (256x256) + out_b, f32 out ----
__global__ __launch_bounds__(256) void out_gemm(const unsigned short* __restrict__ ctx,
                                                const unsigned short* __restrict__ Ob,
                                                const float* __restrict__ out_b,
                                                float* __restrict__ out) {
  int m0 = blockIdx.x * 16;
  int wv = threadIdx.x >> 6, lane = threadIdx.x & 63;
  int lm = lane & 15, g = lane >> 4;
  int n0 = wv * 64;
  f32x4 acc[4] = {};
  for (int k0 = 0; k0 < D_; k0 += 32) {
    bf16x8 a = *reinterpret_cast<const bf16x8*>(ctx + (size_t)(m0 + lm) * D_ + k0 + 8 * g);
#pragma unroll
    for (int j = 0; j < 4; ++j) {
      bf16x8 b = *reinterpret_cast<const bf16x8*>(Ob + (size_t)(n0 + j * 16 + lm) * D_ + k0 + 8 * g);
      acc[j] = mfma16(a, b, acc[j]);
    }
  }
#pragma unroll
  for (int j = 0; j < 4; ++j) {
    int o = n0 + j * 16 + lm;
    float bias = out_b[o];
#pragma unroll
    for (int r = 0; r < 4; ++r) {
      int row = m0 + g * 4 + r;
      out[(size_t)row * D_ + o] = acc[j][r] + bias;
    }
  }
}

extern "C" void kernel_launch(void* const* d_in, const int* in_sizes, int n_in,
                              void* d_out, int out_size, void* d_ws, size_t ws_size,
                              hipStream_t stream) {
  const float* x = (const float*)d_in[0];
  const float* dw_w = (const float*)d_in[1];
  const float* dw_b = (const float*)d_in[2];
  const float* gma = (const float*)d_in[3];
  const float* bta = (const float*)d_in[4];
  const float* mu = (const float*)d_in[5];
  const float* var = (const float*)d_in[6];
  const float* pw_w = (const float*)d_in[7];
  const float* pw_b = (const float*)d_in[8];
  const float* out_w = (const float*)d_in[9];
  const float* out_b = (const float*)d_in[10];
  float* out = (float*)d_out;

  char* ws = (char*)d_ws;
  size_t off = 0;
  auto alloc = [&](size_t bytes) -> void* {
    void* ptr = (void*)(ws + off);
    off += (bytes + 255) & ~(size_t)255;
    return ptr;
  };
  float* wf = (float*)alloc(3 * 256 * 3 * 4);
  float* yb = (float*)alloc(3 * 256 * 4);
  unsigned short* Wb = (unsigned short*)alloc((size_t)3 * 256 * 256 * 2);
  unsigned short* Ob = (unsigned short*)alloc((size_t)256 * 256 * 2);
  unsigned short* Y = (unsigned short*)alloc((size_t)3 * 8192 * 256 * 2);
  unsigned short* Q = (unsigned short*)alloc((size_t)16 * 4096 * 32 * 2);
  unsigned short* Kk = (unsigned short*)alloc((size_t)16 * 4096 * 32 * 2);
  unsigned short* Vt = (unsigned short*)alloc((size_t)16 * 32 * 4096 * 2);
  unsigned short* ctx = (unsigned short*)alloc((size_t)8192 * 256 * 2);

  hipLaunchKernelGGL(prep_bn, dim3(3), dim3(256), 0, stream, dw_w, dw_b, gma, bta, mu, var, wf, yb);
  hipLaunchKernelGGL(cvt_w, dim3(768), dim3(256), 0, stream, pw_w, out_w, Wb, Ob);
  hipLaunchKernelGGL(conv_bn, dim3(8192), dim3(256), 0, stream, x, wf, yb, Y);
  hipLaunchKernelGGL(qkv_gemm, dim3(512, 3), dim3(256), 0, stream, Y, Wb, pw_b, Q, Kk, Vt);
  hipLaunchKernelGGL(attn, dim3(1024), dim3(256), 0, stream, Q, Kk, Vt, ctx);
  hipLaunchKernelGGL(out_gemm, dim3(512), dim3(256), 0, stream, ctx, Ob, out_b, out);
}